// Round 7
// baseline (300.238 us; speedup 1.0000x reference)
//
#include <hip/hip_runtime.h>
#include <hip/hip_bf16.h>

#define TKN   2048
#define CDIM  256
#define PDIM  32
#define ODIM  32
#define HIDD  128
#define CCSZ  65536
#define TOTSZ 66560
#define KSPL  16

typedef unsigned short u16;
typedef __bf16 bf16x8 __attribute__((ext_vector_type(8)));
typedef float f32x4 __attribute__((ext_vector_type(4)));
typedef unsigned short u16x4 __attribute__((ext_vector_type(4)));
typedef unsigned short u16x8 __attribute__((ext_vector_type(8)));

__device__ __forceinline__ u16 f2b(float f){
  __hip_bfloat16 h = __float2bfloat16(f);
  return *reinterpret_cast<u16*>(&h);
}
__device__ __forceinline__ float gelu_exact(float x){
  return 0.5f * x * (1.0f + erff(x * 0.70710678118654752f));
}
// async global->LDS, 16B per lane; LDS dest = wave-uniform base + lane*16 (linear).
__device__ __forceinline__ void gload16(const void* g, void* l){
  __builtin_amdgcn_global_load_lds(
      (const __attribute__((address_space(1))) unsigned int*)g,
      (__attribute__((address_space(3))) unsigned int*)l, 16, 0, 0);
}

// ---------------- prep: layernorm + h = q@w1.T + b1  -> H bf16 [2048][128]
__global__ __launch_bounds__(256) void k_prep_h(
    const float* __restrict__ query, const float* __restrict__ ln_w,
    const float* __restrict__ ln_b, const float* __restrict__ w1,
    const float* __restrict__ b1, u16* __restrict__ H){
  const int t = blockIdx.x;
  const int tid = threadIdx.x;
  __shared__ float qs[CDIM];
  __shared__ float red[8];
  __shared__ float stat[2];
  float v = query[(size_t)t*CDIM + tid];
  float s = v, s2 = v*v;
  #pragma unroll
  for(int o=32;o>0;o>>=1){ s += __shfl_down(s,o,64); s2 += __shfl_down(s2,o,64); }
  const int wv = tid>>6;
  if((tid&63)==0){ red[wv]=s; red[4+wv]=s2; }
  __syncthreads();
  if(tid==0){
    float ss=red[0]+red[1]+red[2]+red[3];
    float qq=red[4]+red[5]+red[6]+red[7];
    float mu=ss/(float)CDIM;
    float var=qq/(float)CDIM - mu*mu;
    stat[0]=mu; stat[1]=rsqrtf(var+1e-6f);
  }
  __syncthreads();
  qs[tid] = (v - stat[0])*stat[1]*ln_w[tid] + ln_b[tid];
  __syncthreads();
  if(tid < HIDD){
    const float* wr = w1 + (size_t)tid*CDIM;
    float acc = b1[tid];
    #pragma unroll 8
    for(int c=0;c<CDIM;c++) acc += qs[c]*wr[c];
    H[(size_t)t*HIDD + tid] = f2b(acc);
  }
}

// ---------------- prep: w2 -> bf16, row-permuted (dst = d*256+c for cm part) + 16B-chunk XOR swizzle; b2 permuted
__global__ __launch_bounds__(256) void k_prep_w2(
    const float* __restrict__ w2, const float* __restrict__ b2,
    u16* __restrict__ w2s, float* __restrict__ b2p){
  const int gid = blockIdx.x*256 + threadIdx.x;   // 66560*16 threads
  const int dst = gid >> 4;
  const int ch  = gid & 15;
  if(dst >= TOTSZ) return;
  const int j = (dst < CCSZ) ? (((dst & 255) << 8) | (dst >> 8)) : dst;
  const float* src = w2 + (size_t)j*HIDD + ch*8;
  u16* o = w2s + (size_t)dst*HIDD + (size_t)((ch ^ (dst & 7))*8);
  u16x8 tv;
  #pragma unroll
  for(int i=0;i<8;i++) tv[i] = f2b(src[i]);
  *(u16x8*)o = tv;
  if(ch == 0) b2p[dst] = b2[j];
}

// ---------------- prep: proj_w -> bf16
__global__ __launch_bounds__(256) void k_prep_pw(
    const float* __restrict__ pw, u16* __restrict__ pwb){
  const int gid = blockIdx.x*256 + threadIdx.x;   // 262144 threads
  const float* s = pw + (size_t)gid*8;
  u16x8 tv;
  #pragma unroll
  for(int i=0;i<8;i++) tv[i] = f2b(s[i]);
  *(u16x8*)(pwb + (size_t)gid*8) = tv;
}

// ---------------- params GEMM v3 (B-resident m-loop + LDS-transposed coalesced C-write):
// grid (520), 512 threads (8 waves: 4 M-groups x 2 N-halves). Each block owns
// n-tile [n0,n0+128), stages B ONCE, then loops msteps m-tiles of 128 rows.
// Output tile goes through ldsO (chunk-XOR-swizzled write, linear b128 read)
// so the global store is u16x8/lane, 256B contiguous per 16 lanes — fixing the
// request-rate-bound scalar-u16 C-write (r6: 1.9 TB/s effective, MfmaUtil 8.8%).
__global__ __launch_bounds__(512) void k_params(
    const u16* __restrict__ H, const u16* __restrict__ w2s,
    const float* __restrict__ b2p, u16* __restrict__ pbuf, int msteps){
  __shared__ u16 ldsB[128*128];
  __shared__ u16 ldsO[128*128];
  const int tid = threadIdx.x;
  const int n0 = blockIdx.x * 128;
  const int lane = tid & 63;
  const int w = tid >> 6;
  // stage B tile (contiguous 32KB of pre-swizzled w2s) via async global_load_lds
  {
    const char* gbase = (const char*)(w2s + (size_t)n0*HIDD) + w*4096 + lane*16;
    #pragma unroll
    for(int i=0;i<4;i++)
      gload16(gbase + i*1024, (char*)ldsB + w*4096 + i*1024);
  }
  const int wmi = w >> 1, wni = w & 1;
  const int r15 = lane & 15, g = lane >> 4;
  // per-column b2 values (constant across m)
  float b2v[4];
  #pragma unroll
  for(int nt=0;nt<4;nt++) b2v[nt] = b2p[n0 + wni*64 + nt*16 + r15];
  __syncthreads();
  // B fragments from LDS (constant across m)
  bf16x8 bfr[4][4];
  #pragma unroll
  for(int ks=0;ks<4;ks++)
    #pragma unroll
    for(int nt=0;nt<4;nt++){
      const int rr = wni*64 + nt*16 + r15;
      const int pc = (ks*4 + g) ^ (rr & 7);
      bfr[ks][nt] = *(const bf16x8*)&ldsB[rr*128 + pc*8];
    }
  for(int m=0; m<msteps; m++){
    const int m0 = m*128;
    bf16x8 afr[2][4];
    #pragma unroll
    for(int mt=0;mt<2;mt++){
      const int row = m0 + wmi*32 + mt*16 + r15;
      const u16* ap = H + (size_t)row*HIDD + g*8;
      #pragma unroll
      for(int ks=0;ks<4;ks++) afr[mt][ks] = *(const bf16x8*)(ap + ks*32);
    }
    f32x4 acc[2][4] = {};
    #pragma unroll
    for(int ks=0;ks<4;ks++)
      #pragma unroll
      for(int mt=0;mt<2;mt++)
        #pragma unroll
        for(int nt=0;nt<4;nt++)
          acc[mt][nt] = __builtin_amdgcn_mfma_f32_16x16x32_bf16(afr[mt][ks], bfr[ks][nt], acc[mt][nt], 0,0,0);
    __syncthreads();   // ldsO free (previous m-step's readers done)
    // epilogue -> ldsO, chunk swizzled: chunk q = (col>>3) ^ (row&15)
    #pragma unroll
    for(int nt=0;nt<4;nt++){
      const int col = wni*64 + nt*16 + r15;
      #pragma unroll
      for(int mt=0;mt<2;mt++){
        const int row0 = wmi*32 + mt*16 + g*4;
        #pragma unroll
        for(int r=0;r<4;r++){
          const int row = row0 + r;
          ldsO[row*128 + (((col>>3) ^ (row&15))<<3) + (col&7)] = f2b(acc[mt][nt][r] + b2v[nt]);
        }
      }
    }
    __syncthreads();
    // coalesced store: lane reads linear 16B from ldsO, writes u16x8; 16 lanes
    // cover one row's 256B (chunk-permuted within the segment — coalescing OK)
    #pragma unroll
    for(int j=0;j<4;j++){
      const int flat = j*512 + tid;      // 0..2047
      const int row  = flat >> 4;        // 0..127
      const int q    = flat & 15;
      const int cc   = q ^ (row & 15);
      *(u16x8*)(pbuf + (size_t)(m0+row)*TOTSZ + n0 + cc*8) =
          *(const u16x8*)&ldsO[row*128 + q*8];
    }
  }
}

// ---------------- per-token chain, d-split: block (tl, dh) handles d in [dh*128, dh*128+128)
__global__ __launch_bounds__(256) void k_token(
    const float* __restrict__ xg, const u16* __restrict__ pbuf,
    const float* __restrict__ m_beta, const float* __restrict__ s_beta,
    u16* __restrict__ out2){
  __shared__ u16 xs[PDIM][264];   // reused as out2 tile [ODIM][<=264] later
  __shared__ u16 smt[ODIM][40];
  __shared__ u16 o1[128][40];
  const int tl = blockIdx.x;
  const int dh = blockIdx.y;
  const int tid = threadIdx.x;
  const int lane = tid & 63;
  const int w = tid >> 6;
  const int r15 = lane & 15, g = lane >> 4;

  // stage xs -> bf16 LDS [p][c] (full, duplicated across the 2 d-half blocks)
  {
    const f32x4* src = (const f32x4*)(xg + (size_t)tl*8192);
    #pragma unroll
    for(int i=0;i<8;i++){
      f32x4 v = src[tid + 256*i];
      const int flat = (tid + 256*i)*4;
      const int p = flat >> 8, c = flat & 255;
      u16x4 t4; t4[0]=f2b(v[0]); t4[1]=f2b(v[1]); t4[2]=f2b(v[2]); t4[3]=f2b(v[3]);
      *(u16x4*)&xs[p][c] = t4;
    }
  }
  // stage sm [o][p]
  if(tid < 128){
    const u16* s = pbuf + (size_t)tl*TOTSZ + CCSZ + tid*8;
    const int o = (tid*8) >> 5, p = (tid*8) & 31;
    *(u16x8*)&smt[o][p] = *(const u16x8*)s;
  }
  __syncthreads();

  // GEMM2: out1T[dloc][p] = sum_c cmT[dh*128+dloc][c]*xs[p][c]
  f32x4 acc[2][2] = {};
  const u16* cmrow = pbuf + (size_t)tl*TOTSZ + (size_t)dh*128*256;
  #pragma unroll
  for(int ks=0;ks<8;ks++){
    bf16x8 af[2], bf[2];
    #pragma unroll
    for(int mt=0;mt<2;mt++){
      const int dloc = w*32 + mt*16 + r15;
      af[mt] = *(const bf16x8*)(cmrow + (size_t)dloc*256 + ks*32 + g*8);
    }
    #pragma unroll
    for(int nt=0;nt<2;nt++){
      const int p = nt*16 + r15;
      bf[nt] = *(const bf16x8*)&xs[p][ks*32 + g*8];
    }
    #pragma unroll
    for(int mt=0;mt<2;mt++)
      #pragma unroll
      for(int nt=0;nt<2;nt++)
        acc[mt][nt] = __builtin_amdgcn_mfma_f32_16x16x32_bf16(af[mt], bf[nt], acc[mt][nt], 0,0,0);
  }
  // epilogue -> o1[dloc][p] (gelu(x + m_beta[d]))
  #pragma unroll
  for(int mt=0;mt<2;mt++){
    const int d0 = w*32 + mt*16 + g*4;
    const f32x4 mb = *(const f32x4*)&m_beta[dh*128 + d0];
    #pragma unroll
    for(int nt=0;nt<2;nt++){
      const int p = nt*16 + r15;
      #pragma unroll
      for(int r=0;r<4;r++)
        o1[d0+r][p] = f2b(gelu_exact(acc[mt][nt][r] + mb[r]));
    }
  }
  __syncthreads();

  // GEMM-sm: out2T[dloc][o] = sum_p o1[dloc][p]*sm[o][p]  (K=32, single step)
  f32x4 acc2[2][2] = {};
  {
    bf16x8 af[2], bf2[2];
    #pragma unroll
    for(int mt=0;mt<2;mt++){
      const int dloc = w*32 + mt*16 + r15;
      af[mt] = *(const bf16x8*)&o1[dloc][g*8];
    }
    #pragma unroll
    for(int nt=0;nt<2;nt++){
      const int o = nt*16 + r15;
      bf2[nt] = *(const bf16x8*)&smt[o][g*8];
    }
    #pragma unroll
    for(int mt=0;mt<2;mt++)
      #pragma unroll
      for(int nt=0;nt<2;nt++)
        acc2[mt][nt] = __builtin_amdgcn_mfma_f32_16x16x32_bf16(af[mt], bf2[nt], acc2[mt][nt], 0,0,0);
  }
  // epilogue into xs buffer reused as out2 tile [o][dloc]
  u16 (*o2t)[264] = xs;
  #pragma unroll
  for(int nt=0;nt<2;nt++){
    const int o = nt*16 + r15;
    const float sb = s_beta[o];
    #pragma unroll
    for(int mt=0;mt<2;mt++){
      const int d0 = w*32 + mt*16 + g*4;
      u16x4 t4;
      #pragma unroll
      for(int r=0;r<4;r++) t4[r] = f2b(gelu_exact(acc2[mt][nt][r] + sb));
      *(u16x4*)&o2t[o][d0] = t4;
    }
  }
  __syncthreads();
  // copy out flat (k = o*256 + dh*128 + dd)
  {
    u16* dst = out2 + (size_t)tl*8192 + dh*128;
    #pragma unroll
    for(int i=0;i<2;i++){
      const int flat = (i*256 + tid)*8;   // over [o][128]
      const int o = flat >> 7, dd = flat & 127;
      *(u16x8*)(dst + o*256 + dd) = *(const u16x8*)&o2t[o][dd];
    }
  }
}

// ---------------- proj GEMM: 2-phase LDS-pipelined. part[kz][t][e] = sum_{k slice} out2[t][k]*pwb[e][k]
// grid (32, KSPL), 512 threads (8 waves: 2M x 4N; wave tile 32x64). BM=64, BN=256, Kslice=512, kstep=32.
__global__ __launch_bounds__(512) void k_proj(
    const u16* __restrict__ out2, const u16* __restrict__ pwb,
    float* __restrict__ part){
  __shared__ u16 Ab[2][64*32];
  __shared__ u16 Bb[2][256*32];
  const int tid = threadIdx.x;
  const int lane = tid & 63, w = tid >> 6;
  const int r15 = lane & 15, g = lane >> 4;
  const int m0 = blockIdx.x * 64;
  const int k0 = blockIdx.y * 512;
  const int wm = (w >> 2) * 32;
  const int wn = (w & 3) * 64;
  const int srow = lane >> 2;
  const int cs   = lane & 3;
  const int a_row = (w & 3)*16 + srow;
  const u16* a_src = out2 + (size_t)(m0 + a_row)*8192 + k0 + (size_t)((cs ^ (a_row & 3))*8);
  const int b_row0 = (2*w)*16 + srow;
  const int b_row1 = (2*w+1)*16 + srow;
  const u16* b_src0 = pwb + (size_t)b_row0*8192 + k0 + (size_t)((cs ^ (b_row0 & 3))*8);
  const u16* b_src1 = pwb + (size_t)b_row1*8192 + k0 + (size_t)((cs ^ (b_row1 & 3))*8);

  f32x4 acc[2][4] = {};

  #define STAGE(buf, kt) do{                                         \
    const int ko = (kt)*32;                                          \
    if(w < 4) gload16(a_src + ko, (char*)&Ab[buf][0] + w*1024);      \
    gload16(b_src0 + ko, (char*)&Bb[buf][0] + (2*w)*1024);           \
    gload16(b_src1 + ko, (char*)&Bb[buf][0] + (2*w+1)*1024);         \
  }while(0)

  STAGE(0, 0);
  __syncthreads();
  int cur = 0;
  for(int kt=0; kt<16; kt++){
    if(kt < 15){ STAGE(cur^1, kt+1); }
    bf16x8 af[2], bf[4];
    #pragma unroll
    for(int mt=0;mt<2;mt++){
      const int row = wm + mt*16 + r15;
      af[mt] = *(const bf16x8*)((char*)&Ab[cur][0] + row*64 + ((g ^ (row&3))*16));
    }
    #pragma unroll
    for(int nt=0;nt<4;nt++){
      const int row = wn + nt*16 + r15;
      bf[nt] = *(const bf16x8*)((char*)&Bb[cur][0] + row*64 + ((g ^ (row&3))*16));
    }
    #pragma unroll
    for(int mt=0;mt<2;mt++)
      #pragma unroll
      for(int nt=0;nt<4;nt++)
        acc[mt][nt] = __builtin_amdgcn_mfma_f32_16x16x32_bf16(af[mt], bf[nt], acc[mt][nt], 0,0,0);
    __syncthreads();
    cur ^= 1;
  }
  #undef STAGE

  float* pbase = part + (size_t)blockIdx.y*TKN*CDIM;
  #pragma unroll
  for(int mt=0;mt<2;mt++)
    #pragma unroll
    for(int nt=0;nt<4;nt++){
      const int t = m0 + wm + mt*16 + g*4;
      const int e = wn + nt*16 + r15;
      #pragma unroll
      for(int r=0;r<4;r++)
        pbase[(size_t)(t+r)*CDIM + e] = acc[mt][nt][r];
    }
}

// ---------------- combine partials + proj_b (f32x4 vectorized)
// 131072 threads total = 512 blocks x 256 (each thread owns one f32x4)
__global__ __launch_bounds__(256) void k_combine(
    const float* __restrict__ part, const float* __restrict__ pb,
    float* __restrict__ out){
  const int i4 = blockIdx.x*256 + threadIdx.x;   // 131072 f32x4's
  const int e4 = (i4 & 63)*4;
  f32x4 s = *(const f32x4*)&pb[e4];
  #pragma unroll
  for(int z=0;z<KSPL;z++) s += *(const f32x4*)&part[(size_t)z*524288 + (size_t)i4*4];
  *(f32x4*)&out[(size_t)i4*4] = s;
}

extern "C" void kernel_launch(void* const* d_in, const int* in_sizes, int n_in,
                              void* d_out, int out_size, void* d_ws, size_t ws_size,
                              hipStream_t stream){
  const float* x     = (const float*)d_in[0];
  const float* query = (const float*)d_in[1];
  const float* ln_w  = (const float*)d_in[2];
  const float* ln_b  = (const float*)d_in[3];
  const float* w1    = (const float*)d_in[4];
  const float* b1    = (const float*)d_in[5];
  const float* w2    = (const float*)d_in[6];
  const float* b2    = (const float*)d_in[7];
  const float* m_beta= (const float*)d_in[8];
  const float* s_beta= (const float*)d_in[9];
  const float* pw    = (const float*)d_in[10];
  const float* pb    = (const float*)d_in[11];
  float* out = (float*)d_out;
  char* ws = (char*)d_ws;

  // chunk size chosen from ws_size (deterministic: ws_size is fixed).
  // Big path needs ~192 MB (measured ws = 256 MiB).
  const size_t need_big = 192u*1024u*1024u;
  const int chnk = (ws_size >= need_big) ? 1024 : 256;
  const int nch  = TKN / chnk;

  size_t off = 0;
  u16* H     = (u16*)(ws + off);  off += (size_t)TKN*HIDD*2;
  u16* w2s   = (u16*)(ws + off);  off += (size_t)TOTSZ*HIDD*2;
  float* b2p = (float*)(ws + off);off += (size_t)TOTSZ*4;
  u16* pwb   = (u16*)(ws + off);  off += (size_t)CDIM*8192*2;
  u16* pbuf  = (u16*)(ws + off);  off += (size_t)chnk*TOTSZ*2;
  u16* out2  = (u16*)(ws + off);  off += (size_t)TKN*8192*2;
  // part (16 x 2048 x 256 fp32 = 33.55 MB) aliases pbuf (>=34 MB, dead by k_proj).
  float* part= (float*)pbuf;

  k_prep_h<<<TKN, 256, 0, stream>>>(query, ln_w, ln_b, w1, b1, H);
  k_prep_w2<<<4160, 256, 0, stream>>>(w2, b2, w2s, b2p);
  k_prep_pw<<<1024, 256, 0, stream>>>(pw, pwb);
  for(int ch=0; ch<nch; ch++){
    k_params<<<520, 512, 0, stream>>>(H + (size_t)ch*chnk*HIDD, w2s, b2p, pbuf, chnk/128);
    k_token<<<dim3(chnk,2), 256, 0, stream>>>(x + (size_t)ch*chnk*8192, pbuf, m_beta, s_beta,
                                              out2 + (size_t)ch*chnk*8192);
  }
  k_proj<<<dim3(32,KSPL), 512, 0, stream>>>(out2, pwb, part);
  k_combine<<<512, 256, 0, stream>>>(part, pb, out);
}

// Round 8
// 290.672 us; speedup vs baseline: 1.0329x; 1.0329x over previous
//
#include <hip/hip_runtime.h>
#include <hip/hip_bf16.h>

#define TKN   2048
#define CDIM  256
#define PDIM  32
#define ODIM  32
#define HIDD  128
#define CCSZ  65536
#define TOTSZ 66560
#define KSPL  16

typedef unsigned short u16;
typedef __bf16 bf16x8 __attribute__((ext_vector_type(8)));
typedef float f32x4 __attribute__((ext_vector_type(4)));
typedef unsigned short u16x4 __attribute__((ext_vector_type(4)));
typedef unsigned short u16x8 __attribute__((ext_vector_type(8)));

__device__ __forceinline__ u16 f2b(float f){
  __hip_bfloat16 h = __float2bfloat16(f);
  return *reinterpret_cast<u16*>(&h);
}
__device__ __forceinline__ float gelu_exact(float x){
  return 0.5f * x * (1.0f + erff(x * 0.70710678118654752f));
}
// async global->LDS, 16B per lane; LDS dest = wave-uniform base + lane*16 (linear).
__device__ __forceinline__ void gload16(const void* g, void* l){
  __builtin_amdgcn_global_load_lds(
      (const __attribute__((address_space(1))) unsigned int*)g,
      (__attribute__((address_space(3))) unsigned int*)l, 16, 0, 0);
}

// ---------------- prep: layernorm + h = q@w1.T + b1  -> H bf16 [2048][128]
__global__ __launch_bounds__(256) void k_prep_h(
    const float* __restrict__ query, const float* __restrict__ ln_w,
    const float* __restrict__ ln_b, const float* __restrict__ w1,
    const float* __restrict__ b1, u16* __restrict__ H){
  const int t = blockIdx.x;
  const int tid = threadIdx.x;
  __shared__ float qs[CDIM];
  __shared__ float red[8];
  __shared__ float stat[2];
  float v = query[(size_t)t*CDIM + tid];
  float s = v, s2 = v*v;
  #pragma unroll
  for(int o=32;o>0;o>>=1){ s += __shfl_down(s,o,64); s2 += __shfl_down(s2,o,64); }
  const int wv = tid>>6;
  if((tid&63)==0){ red[wv]=s; red[4+wv]=s2; }
  __syncthreads();
  if(tid==0){
    float ss=red[0]+red[1]+red[2]+red[3];
    float qq=red[4]+red[5]+red[6]+red[7];
    float mu=ss/(float)CDIM;
    float var=qq/(float)CDIM - mu*mu;
    stat[0]=mu; stat[1]=rsqrtf(var+1e-6f);
  }
  __syncthreads();
  qs[tid] = (v - stat[0])*stat[1]*ln_w[tid] + ln_b[tid];
  __syncthreads();
  if(tid < HIDD){
    const float* wr = w1 + (size_t)tid*CDIM;
    float acc = b1[tid];
    #pragma unroll 8
    for(int c=0;c<CDIM;c++) acc += qs[c]*wr[c];
    H[(size_t)t*HIDD + tid] = f2b(acc);
  }
}

// ---------------- prep: w2 -> bf16, row-permuted (dst = d*256+c for cm part) + 16B-chunk XOR swizzle; b2 permuted
__global__ __launch_bounds__(256) void k_prep_w2(
    const float* __restrict__ w2, const float* __restrict__ b2,
    u16* __restrict__ w2s, float* __restrict__ b2p){
  const int gid = blockIdx.x*256 + threadIdx.x;   // 66560*16 threads
  const int dst = gid >> 4;
  const int ch  = gid & 15;
  if(dst >= TOTSZ) return;
  const int j = (dst < CCSZ) ? (((dst & 255) << 8) | (dst >> 8)) : dst;
  const float* src = w2 + (size_t)j*HIDD + ch*8;
  u16* o = w2s + (size_t)dst*HIDD + (size_t)((ch ^ (dst & 7))*8);
  u16x8 tv;
  #pragma unroll
  for(int i=0;i<8;i++) tv[i] = f2b(src[i]);
  *(u16x8*)o = tv;
  if(ch == 0) b2p[dst] = b2[j];
}

// ---------------- prep: proj_w -> bf16
__global__ __launch_bounds__(256) void k_prep_pw(
    const float* __restrict__ pw, u16* __restrict__ pwb){
  const int gid = blockIdx.x*256 + threadIdx.x;   // 262144 threads
  const float* s = pw + (size_t)gid*8;
  u16x8 tv;
  #pragma unroll
  for(int i=0;i<8;i++) tv[i] = f2b(s[i]);
  *(u16x8*)(pwb + (size_t)gid*8) = tv;
}

// ---------------- params GEMM v4 (B-resident m-loop + panel-contiguous C-write):
// pbuf layout: PANELS [q][chnk][128], q = dst>>7 (520 panels). Block b owns
// panel q=b: each m-step writes ONE CONTIGUOUS 32KB block (fixes r7's
// page-scattered 256B writes @1.8 TB/s). Output staged through ldsBuf
// (reused: B-tile is reg-resident after prologue) -> 32KB LDS, 4 blocks/CU.
__global__ __launch_bounds__(512) void k_params(
    const u16* __restrict__ H, const u16* __restrict__ w2s,
    const float* __restrict__ b2p, u16* __restrict__ pbuf, int msteps, int chnk){
  __shared__ u16 ldsBuf[128*128];   // B-tile in prologue, O-tile in m-loop
  const int tid = threadIdx.x;
  const int n0 = blockIdx.x * 128;
  const int lane = tid & 63;
  const int w = tid >> 6;
  // stage B tile (contiguous 32KB of pre-swizzled w2s) via async global_load_lds
  {
    const char* gbase = (const char*)(w2s + (size_t)n0*HIDD) + w*4096 + lane*16;
    #pragma unroll
    for(int i=0;i<4;i++)
      gload16(gbase + i*1024, (char*)ldsBuf + w*4096 + i*1024);
  }
  const int wmi = w >> 1, wni = w & 1;
  const int r15 = lane & 15, g = lane >> 4;
  float b2v[4];
  #pragma unroll
  for(int nt=0;nt<4;nt++) b2v[nt] = b2p[n0 + wni*64 + nt*16 + r15];
  __syncthreads();
  // B fragments -> registers (constant across m); ldsBuf dead afterwards
  bf16x8 bfr[4][4];
  #pragma unroll
  for(int ks=0;ks<4;ks++)
    #pragma unroll
    for(int nt=0;nt<4;nt++){
      const int rr = wni*64 + nt*16 + r15;
      const int pc = (ks*4 + g) ^ (rr & 7);
      bfr[ks][nt] = *(const bf16x8*)&ldsBuf[rr*128 + pc*8];
    }
  u16* opanel = pbuf + (size_t)blockIdx.x*chnk*128;
  for(int m=0; m<msteps; m++){
    const int m0 = m*128;
    bf16x8 afr[2][4];
    #pragma unroll
    for(int mt=0;mt<2;mt++){
      const int row = m0 + wmi*32 + mt*16 + r15;
      const u16* ap = H + (size_t)row*HIDD + g*8;
      #pragma unroll
      for(int ks=0;ks<4;ks++) afr[mt][ks] = *(const bf16x8*)(ap + ks*32);
    }
    f32x4 acc[2][4] = {};
    #pragma unroll
    for(int ks=0;ks<4;ks++)
      #pragma unroll
      for(int mt=0;mt<2;mt++)
        #pragma unroll
        for(int nt=0;nt<4;nt++)
          acc[mt][nt] = __builtin_amdgcn_mfma_f32_16x16x32_bf16(afr[mt][ks], bfr[ks][nt], acc[mt][nt], 0,0,0);
    __syncthreads();   // prev m-step's copy-out reads done (also 1st iter: bfr reads done)
    // epilogue -> ldsBuf as O-tile, chunk swizzled: chunk slot = (col>>3) ^ (row&15)
    #pragma unroll
    for(int nt=0;nt<4;nt++){
      const int col = wni*64 + nt*16 + r15;
      #pragma unroll
      for(int mt=0;mt<2;mt++){
        const int row0 = wmi*32 + mt*16 + g*4;
        #pragma unroll
        for(int r=0;r<4;r++){
          const int row = row0 + r;
          ldsBuf[row*128 + (((col>>3) ^ (row&15))<<3) + (col&7)] = f2b(acc[mt][nt][r] + b2v[nt]);
        }
      }
    }
    __syncthreads();
    // copy out: linear 16B/lane LDS reads -> contiguous 32KB global stream
    // (cols permuted within each 256B row segment — coalescing unaffected)
    u16* dst = opanel + (size_t)m0*128;
    #pragma unroll
    for(int j=0;j<4;j++){
      const int flat = j*512 + tid;      // 0..2047 16B-units
      const int row  = flat >> 4;
      const int q    = flat & 15;
      const int cc   = q ^ (row & 15);
      *(u16x8*)(dst + row*128 + cc*8) = *(const u16x8*)&ldsBuf[row*128 + q*8];
    }
  }
}

// ---------------- per-token chain, d-split: block (tl, dh) handles d in [dh*128, dh*128+128)
// pbuf is panel-layout: elem addr = (q*chnk + tl)*128 + (dst&127), q = dst>>7
__global__ __launch_bounds__(256) void k_token(
    const float* __restrict__ xg, const u16* __restrict__ pbuf,
    const float* __restrict__ m_beta, const float* __restrict__ s_beta,
    u16* __restrict__ out2, int chnk){
  __shared__ u16 xs[PDIM][264];   // reused as out2 tile [ODIM][<=264] later
  __shared__ u16 smt[ODIM][40];
  __shared__ u16 o1[128][40];
  const int tl = blockIdx.x;
  const int dh = blockIdx.y;
  const int tid = threadIdx.x;
  const int lane = tid & 63;
  const int w = tid >> 6;
  const int r15 = lane & 15, g = lane >> 4;
  const size_t prow = (size_t)chnk*128;   // panel size in elems

  // stage xs -> bf16 LDS [p][c] (full, duplicated across the 2 d-half blocks)
  {
    const f32x4* src = (const f32x4*)(xg + (size_t)tl*8192);
    #pragma unroll
    for(int i=0;i<8;i++){
      f32x4 v = src[tid + 256*i];
      const int flat = (tid + 256*i)*4;
      const int p = flat >> 8, c = flat & 255;
      u16x4 t4; t4[0]=f2b(v[0]); t4[1]=f2b(v[1]); t4[2]=f2b(v[2]); t4[3]=f2b(v[3]);
      *(u16x4*)&xs[p][c] = t4;
    }
  }
  // stage sm [o][p]: dst = CCSZ + tid*8 -> panel q = 512 + (tid>>4)
  if(tid < 128){
    const u16* s = pbuf + ((size_t)(512 + (tid>>4)))*prow + (size_t)tl*128 + (tid&15)*8;
    const int o = (tid*8) >> 5, p = (tid*8) & 31;
    *(u16x8*)&smt[o][p] = *(const u16x8*)s;
  }
  __syncthreads();

  // GEMM2: out1T[dloc][p] = sum_c cmT[d][c]*xs[p][c]; cm panel q = 2d + (c>>7)
  f32x4 acc[2][2] = {};
  const u16* cbase = pbuf + (size_t)(dh*128)*2*prow + (size_t)tl*128;
  #pragma unroll
  for(int ks=0;ks<8;ks++){
    bf16x8 af[2], bf[2];
    #pragma unroll
    for(int mt=0;mt<2;mt++){
      const int dloc = w*32 + mt*16 + r15;
      af[mt] = *(const bf16x8*)(cbase + (size_t)dloc*2*prow + (size_t)(ks>>2)*prow + (ks&3)*32 + g*8);
    }
    #pragma unroll
    for(int nt=0;nt<2;nt++){
      const int p = nt*16 + r15;
      bf[nt] = *(const bf16x8*)&xs[p][ks*32 + g*8];
    }
    #pragma unroll
    for(int mt=0;mt<2;mt++)
      #pragma unroll
      for(int nt=0;nt<2;nt++)
        acc[mt][nt] = __builtin_amdgcn_mfma_f32_16x16x32_bf16(af[mt], bf[nt], acc[mt][nt], 0,0,0);
  }
  // epilogue -> o1[dloc][p] (gelu(x + m_beta[d]))
  #pragma unroll
  for(int mt=0;mt<2;mt++){
    const int d0 = w*32 + mt*16 + g*4;
    const f32x4 mb = *(const f32x4*)&m_beta[dh*128 + d0];
    #pragma unroll
    for(int nt=0;nt<2;nt++){
      const int p = nt*16 + r15;
      #pragma unroll
      for(int r=0;r<4;r++)
        o1[d0+r][p] = f2b(gelu_exact(acc[mt][nt][r] + mb[r]));
    }
  }
  __syncthreads();

  // GEMM-sm: out2T[dloc][o] = sum_p o1[dloc][p]*sm[o][p]  (K=32, single step)
  f32x4 acc2[2][2] = {};
  {
    bf16x8 af[2], bf2[2];
    #pragma unroll
    for(int mt=0;mt<2;mt++){
      const int dloc = w*32 + mt*16 + r15;
      af[mt] = *(const bf16x8*)&o1[dloc][g*8];
    }
    #pragma unroll
    for(int nt=0;nt<2;nt++){
      const int o = nt*16 + r15;
      bf2[nt] = *(const bf16x8*)&smt[o][g*8];
    }
    #pragma unroll
    for(int mt=0;mt<2;mt++)
      #pragma unroll
      for(int nt=0;nt<2;nt++)
        acc2[mt][nt] = __builtin_amdgcn_mfma_f32_16x16x32_bf16(af[mt], bf2[nt], acc2[mt][nt], 0,0,0);
  }
  // epilogue into xs buffer reused as out2 tile [o][dloc]
  u16 (*o2t)[264] = xs;
  #pragma unroll
  for(int nt=0;nt<2;nt++){
    const int o = nt*16 + r15;
    const float sb = s_beta[o];
    #pragma unroll
    for(int mt=0;mt<2;mt++){
      const int d0 = w*32 + mt*16 + g*4;
      u16x4 t4;
      #pragma unroll
      for(int r=0;r<4;r++) t4[r] = f2b(gelu_exact(acc2[mt][nt][r] + sb));
      *(u16x4*)&o2t[o][d0] = t4;
    }
  }
  __syncthreads();
  // copy out flat (k = o*256 + dh*128 + dd)
  {
    u16* dst = out2 + (size_t)tl*8192 + dh*128;
    #pragma unroll
    for(int i=0;i<2;i++){
      const int flat = (i*256 + tid)*8;   // over [o][128]
      const int o = flat >> 7, dd = flat & 127;
      *(u16x8*)(dst + o*256 + dd) = *(const u16x8*)&o2t[o][dd];
    }
  }
}

// ---------------- proj GEMM: 2-phase LDS-pipelined. part[kz][t][e] = sum_{k slice} out2[t][k]*pwb[e][k]
// grid (32, KSPL), 512 threads (8 waves: 2M x 4N; wave tile 32x64). BM=64, BN=256, Kslice=512, kstep=32.
__global__ __launch_bounds__(512) void k_proj(
    const u16* __restrict__ out2, const u16* __restrict__ pwb,
    float* __restrict__ part){
  __shared__ u16 Ab[2][64*32];
  __shared__ u16 Bb[2][256*32];
  const int tid = threadIdx.x;
  const int lane = tid & 63, w = tid >> 6;
  const int r15 = lane & 15, g = lane >> 4;
  const int m0 = blockIdx.x * 64;
  const int k0 = blockIdx.y * 512;
  const int wm = (w >> 2) * 32;
  const int wn = (w & 3) * 64;
  const int srow = lane >> 2;
  const int cs   = lane & 3;
  const int a_row = (w & 3)*16 + srow;
  const u16* a_src = out2 + (size_t)(m0 + a_row)*8192 + k0 + (size_t)((cs ^ (a_row & 3))*8);
  const int b_row0 = (2*w)*16 + srow;
  const int b_row1 = (2*w+1)*16 + srow;
  const u16* b_src0 = pwb + (size_t)b_row0*8192 + k0 + (size_t)((cs ^ (b_row0 & 3))*8);
  const u16* b_src1 = pwb + (size_t)b_row1*8192 + k0 + (size_t)((cs ^ (b_row1 & 3))*8);

  f32x4 acc[2][4] = {};

  #define STAGE(buf, kt) do{                                         \
    const int ko = (kt)*32;                                          \
    if(w < 4) gload16(a_src + ko, (char*)&Ab[buf][0] + w*1024);      \
    gload16(b_src0 + ko, (char*)&Bb[buf][0] + (2*w)*1024);           \
    gload16(b_src1 + ko, (char*)&Bb[buf][0] + (2*w+1)*1024);         \
  }while(0)

  STAGE(0, 0);
  __syncthreads();
  int cur = 0;
  for(int kt=0; kt<16; kt++){
    if(kt < 15){ STAGE(cur^1, kt+1); }
    bf16x8 af[2], bf[4];
    #pragma unroll
    for(int mt=0;mt<2;mt++){
      const int row = wm + mt*16 + r15;
      af[mt] = *(const bf16x8*)((char*)&Ab[cur][0] + row*64 + ((g ^ (row&3))*16));
    }
    #pragma unroll
    for(int nt=0;nt<4;nt++){
      const int row = wn + nt*16 + r15;
      bf[nt] = *(const bf16x8*)((char*)&Bb[cur][0] + row*64 + ((g ^ (row&3))*16));
    }
    #pragma unroll
    for(int mt=0;mt<2;mt++)
      #pragma unroll
      for(int nt=0;nt<4;nt++)
        acc[mt][nt] = __builtin_amdgcn_mfma_f32_16x16x32_bf16(af[mt], bf[nt], acc[mt][nt], 0,0,0);
    __syncthreads();
    cur ^= 1;
  }
  #undef STAGE

  float* pbase = part + (size_t)blockIdx.y*TKN*CDIM;
  #pragma unroll
  for(int mt=0;mt<2;mt++)
    #pragma unroll
    for(int nt=0;nt<4;nt++){
      const int t = m0 + wm + mt*16 + g*4;
      const int e = wn + nt*16 + r15;
      #pragma unroll
      for(int r=0;r<4;r++)
        pbase[(size_t)(t+r)*CDIM + e] = acc[mt][nt][r];
    }
}

// ---------------- combine partials + proj_b (f32x4 vectorized)
// 131072 threads total = 512 blocks x 256 (each thread owns one f32x4)
__global__ __launch_bounds__(256) void k_combine(
    const float* __restrict__ part, const float* __restrict__ pb,
    float* __restrict__ out){
  const int i4 = blockIdx.x*256 + threadIdx.x;   // 131072 f32x4's
  const int e4 = (i4 & 63)*4;
  f32x4 s = *(const f32x4*)&pb[e4];
  #pragma unroll
  for(int z=0;z<KSPL;z++) s += *(const f32x4*)&part[(size_t)z*524288 + (size_t)i4*4];
  *(f32x4*)&out[(size_t)i4*4] = s;
}

extern "C" void kernel_launch(void* const* d_in, const int* in_sizes, int n_in,
                              void* d_out, int out_size, void* d_ws, size_t ws_size,
                              hipStream_t stream){
  const float* x     = (const float*)d_in[0];
  const float* query = (const float*)d_in[1];
  const float* ln_w  = (const float*)d_in[2];
  const float* ln_b  = (const float*)d_in[3];
  const float* w1    = (const float*)d_in[4];
  const float* b1    = (const float*)d_in[5];
  const float* w2    = (const float*)d_in[6];
  const float* b2    = (const float*)d_in[7];
  const float* m_beta= (const float*)d_in[8];
  const float* s_beta= (const float*)d_in[9];
  const float* pw    = (const float*)d_in[10];
  const float* pb    = (const float*)d_in[11];
  float* out = (float*)d_out;
  char* ws = (char*)d_ws;

  // chunk size chosen from ws_size (deterministic: ws_size is fixed).
  // Big path needs ~192 MB (measured ws = 256 MiB).
  const size_t need_big = 192u*1024u*1024u;
  const int chnk = (ws_size >= need_big) ? 1024 : 256;
  const int nch  = TKN / chnk;

  size_t off = 0;
  u16* H     = (u16*)(ws + off);  off += (size_t)TKN*HIDD*2;
  u16* w2s   = (u16*)(ws + off);  off += (size_t)TOTSZ*HIDD*2;
  float* b2p = (float*)(ws + off);off += (size_t)TOTSZ*4;
  u16* pwb   = (u16*)(ws + off);  off += (size_t)CDIM*8192*2;
  u16* pbuf  = (u16*)(ws + off);  off += (size_t)chnk*TOTSZ*2;   // 520 panels x chnk x 128
  u16* out2  = (u16*)(ws + off);  off += (size_t)TKN*8192*2;
  // part (16 x 2048 x 256 fp32 = 33.55 MB) aliases pbuf (>=34 MB, dead by k_proj).
  float* part= (float*)pbuf;

  k_prep_h<<<TKN, 256, 0, stream>>>(query, ln_w, ln_b, w1, b1, H);
  k_prep_w2<<<4160, 256, 0, stream>>>(w2, b2, w2s, b2p);
  k_prep_pw<<<1024, 256, 0, stream>>>(pw, pwb);
  for(int ch=0; ch<nch; ch++){
    k_params<<<520, 512, 0, stream>>>(H + (size_t)ch*chnk*HIDD, w2s, b2p, pbuf, chnk/128, chnk);
    k_token<<<dim3(chnk,2), 256, 0, stream>>>(x + (size_t)ch*chnk*8192, pbuf, m_beta, s_beta,
                                              out2 + (size_t)ch*chnk*8192, chnk);
  }
  k_proj<<<dim3(32,KSPL), 512, 0, stream>>>(out2, pwb, part);
  k_combine<<<512, 256, 0, stream>>>(part, pb, out);
}

// Round 9
// 256.242 us; speedup vs baseline: 1.1717x; 1.1344x over previous
//
#include <hip/hip_runtime.h>
#include <hip/hip_bf16.h>

#define TKN   2048
#define CDIM  256
#define PDIM  32
#define ODIM  32
#define HIDD  128
#define CCSZ  65536
#define TOTSZ 66560
#define KSPL  16

typedef unsigned short u16;
typedef __bf16 bf16x8 __attribute__((ext_vector_type(8)));
typedef float f32x4 __attribute__((ext_vector_type(4)));
typedef unsigned short u16x4 __attribute__((ext_vector_type(4)));
typedef unsigned short u16x8 __attribute__((ext_vector_type(8)));

__device__ __forceinline__ u16 f2b(float f){
  __hip_bfloat16 h = __float2bfloat16(f);
  return *reinterpret_cast<u16*>(&h);
}
__device__ __forceinline__ float gelu_exact(float x){
  return 0.5f * x * (1.0f + erff(x * 0.70710678118654752f));
}
// async global->LDS, 16B per lane; LDS dest = wave-uniform base + lane*16 (linear).
__device__ __forceinline__ void gload16(const void* g, void* l){
  __builtin_amdgcn_global_load_lds(
      (const __attribute__((address_space(1))) unsigned int*)g,
      (__attribute__((address_space(3))) unsigned int*)l, 16, 0, 0);
}

// ---------------- prep: layernorm + h = q@w1.T + b1  -> H bf16 [2048][128]
__global__ __launch_bounds__(256) void k_prep_h(
    const float* __restrict__ query, const float* __restrict__ ln_w,
    const float* __restrict__ ln_b, const float* __restrict__ w1,
    const float* __restrict__ b1, u16* __restrict__ H){
  const int t = blockIdx.x;
  const int tid = threadIdx.x;
  __shared__ float qs[CDIM];
  __shared__ float red[8];
  __shared__ float stat[2];
  float v = query[(size_t)t*CDIM + tid];
  float s = v, s2 = v*v;
  #pragma unroll
  for(int o=32;o>0;o>>=1){ s += __shfl_down(s,o,64); s2 += __shfl_down(s2,o,64); }
  const int wv = tid>>6;
  if((tid&63)==0){ red[wv]=s; red[4+wv]=s2; }
  __syncthreads();
  if(tid==0){
    float ss=red[0]+red[1]+red[2]+red[3];
    float qq=red[4]+red[5]+red[6]+red[7];
    float mu=ss/(float)CDIM;
    float var=qq/(float)CDIM - mu*mu;
    stat[0]=mu; stat[1]=rsqrtf(var+1e-6f);
  }
  __syncthreads();
  qs[tid] = (v - stat[0])*stat[1]*ln_w[tid] + ln_b[tid];
  __syncthreads();
  if(tid < HIDD){
    const float* wr = w1 + (size_t)tid*CDIM;
    float acc = b1[tid];
    #pragma unroll 8
    for(int c=0;c<CDIM;c++) acc += qs[c]*wr[c];
    H[(size_t)t*HIDD + tid] = f2b(acc);
  }
}

// ---------------- prep: w2 -> bf16, row-permuted (dst = d*256+c for cm part) + 16B-chunk XOR swizzle; b2 permuted
__global__ __launch_bounds__(256) void k_prep_w2(
    const float* __restrict__ w2, const float* __restrict__ b2,
    u16* __restrict__ w2s, float* __restrict__ b2p){
  const int gid = blockIdx.x*256 + threadIdx.x;   // 66560*16 threads
  const int dst = gid >> 4;
  const int ch  = gid & 15;
  if(dst >= TOTSZ) return;
  const int j = (dst < CCSZ) ? (((dst & 255) << 8) | (dst >> 8)) : dst;
  const float* src = w2 + (size_t)j*HIDD + ch*8;
  u16* o = w2s + (size_t)dst*HIDD + (size_t)((ch ^ (dst & 7))*8);
  u16x8 tv;
  #pragma unroll
  for(int i=0;i<8;i++) tv[i] = f2b(src[i]);
  *(u16x8*)o = tv;
  if(ch == 0) b2p[dst] = b2[j];
}

// ---------------- prep: proj_w -> bf16
__global__ __launch_bounds__(256) void k_prep_pw(
    const float* __restrict__ pw, u16* __restrict__ pwb){
  const int gid = blockIdx.x*256 + threadIdx.x;   // 262144 threads
  const float* s = pw + (size_t)gid*8;
  u16x8 tv;
  #pragma unroll
  for(int i=0;i<8;i++) tv[i] = f2b(s[i]);
  *(u16x8*)(pwb + (size_t)gid*8) = tv;
}

// ---------------- params GEMM v5 (BARRIER-FREE m-loop, per-wave LDS transpose):
// grid (520, 2), 256 threads = 4 waves (wmi 2 x wni 2; wave tile 32 tok x 64 n).
// Each block: n-panel q=blockIdx.x, token half blockIdx.y. B-frags loaded ONCE
// directly from pre-swizzled w2s (global). m-loop has ZERO __syncthreads:
// each wave transposes its C-frags through a PRIVATE LDS slice S[w] and issues
// fire-and-forget coalesced stores (8 tokens x 128B per inst). Fixes r6-r8's
// barrier-vmcnt(0) store-drain serialization (write BW pinned at 1.8 TB/s).
__global__ __launch_bounds__(256, 3) void k_params(
    const u16* __restrict__ H, const u16* __restrict__ w2s,
    const float* __restrict__ b2p, u16* __restrict__ pbuf,
    int msteps, int chnk){
  __shared__ __align__(16) u16 S[4][32][72];   // per-wave slices; 72-pad: 16B rows, bank-spread
  const int tid = threadIdx.x;
  const int lane = tid & 63;
  const int w = tid >> 6;
  const int n0 = blockIdx.x * 128;
  const int tbase = blockIdx.y * (chnk >> 1);
  const int wmi = w >> 1, wni = w & 1;
  const int r15 = lane & 15, g = lane >> 4;
  // B fragments direct from global w2s (L2/L3-resident), once per block
  bf16x8 bfr[4][4];
  #pragma unroll
  for(int ks=0;ks<4;ks++)
    #pragma unroll
    for(int nt=0;nt<4;nt++){
      const int rr = wni*64 + nt*16 + r15;          // row within 128-n-tile
      const int pc = (ks*4 + g) ^ (rr & 7);         // pre-swizzle inverse
      bfr[ks][nt] = *(const bf16x8*)(w2s + (size_t)(n0+rr)*HIDD + pc*8);
    }
  float b2v[4];
  #pragma unroll
  for(int nt=0;nt<4;nt++) b2v[nt] = b2p[n0 + wni*64 + nt*16 + r15];
  const int jrow = lane >> 3, jc8 = lane & 7;       // copy-out decomposition
  for(int m=0; m<msteps; m++){
    const int t0 = tbase + m*64 + wmi*32;           // wave's first token (chunk-local)
    bf16x8 afr[2][4];
    #pragma unroll
    for(int mt=0;mt<2;mt++){
      const u16* ap = H + (size_t)(t0 + mt*16 + r15)*HIDD + g*8;
      #pragma unroll
      for(int ks=0;ks<4;ks++) afr[mt][ks] = *(const bf16x8*)(ap + ks*32);
    }
    f32x4 acc[2][4] = {};
    #pragma unroll
    for(int ks=0;ks<4;ks++)
      #pragma unroll
      for(int mt=0;mt<2;mt++)
        #pragma unroll
        for(int nt=0;nt<4;nt++)
          acc[mt][nt] = __builtin_amdgcn_mfma_f32_16x16x32_bf16(afr[mt][ks], bfr[ks][nt], acc[mt][nt], 0,0,0);
    // per-wave transpose: C-frag (4 rows x 1 col per lane) -> S[w][row][col]
    #pragma unroll
    for(int mt=0;mt<2;mt++)
      #pragma unroll
      for(int nt=0;nt<4;nt++)
        #pragma unroll
        for(int r=0;r<4;r++)
          S[w][mt*16 + g*4 + r][nt*16 + r15] = f2b(acc[mt][nt][r] + b2v[nt]);
    // copy-out: u16x8/lane; 8 lanes cover one token's 128B; 8 tokens/inst
    u16* dst = pbuf + ((size_t)blockIdx.x*chnk + t0)*128 + wni*64;
    #pragma unroll
    for(int j=0;j<4;j++){
      const int lt = j*8 + jrow;
      *(u16x8*)(dst + (size_t)lt*128 + jc8*8) = *(const u16x8*)&S[w][lt][jc8*8];
    }
  }
}

// ---------------- per-token chain, d-split: block (tl, dh) handles d in [dh*128, dh*128+128)
// pbuf is panel-layout: elem addr = (q*chnk + tl)*128 + (dst&127), q = dst>>7
__global__ __launch_bounds__(256) void k_token(
    const float* __restrict__ xg, const u16* __restrict__ pbuf,
    const float* __restrict__ m_beta, const float* __restrict__ s_beta,
    u16* __restrict__ out2, int chnk){
  __shared__ u16 xs[PDIM][264];   // reused as out2 tile [ODIM][<=264] later
  __shared__ u16 smt[ODIM][40];
  __shared__ u16 o1[128][40];
  const int tl = blockIdx.x;
  const int dh = blockIdx.y;
  const int tid = threadIdx.x;
  const int lane = tid & 63;
  const int w = tid >> 6;
  const int r15 = lane & 15, g = lane >> 4;
  const size_t prow = (size_t)chnk*128;   // panel size in elems

  // stage xs -> bf16 LDS [p][c] (full, duplicated across the 2 d-half blocks)
  {
    const f32x4* src = (const f32x4*)(xg + (size_t)tl*8192);
    #pragma unroll
    for(int i=0;i<8;i++){
      f32x4 v = src[tid + 256*i];
      const int flat = (tid + 256*i)*4;
      const int p = flat >> 8, c = flat & 255;
      u16x4 t4; t4[0]=f2b(v[0]); t4[1]=f2b(v[1]); t4[2]=f2b(v[2]); t4[3]=f2b(v[3]);
      *(u16x4*)&xs[p][c] = t4;
    }
  }
  // stage sm [o][p]: dst = CCSZ + tid*8 -> panel q = 512 + (tid>>4)
  if(tid < 128){
    const u16* s = pbuf + ((size_t)(512 + (tid>>4)))*prow + (size_t)tl*128 + (tid&15)*8;
    const int o = (tid*8) >> 5, p = (tid*8) & 31;
    *(u16x8*)&smt[o][p] = *(const u16x8*)s;
  }
  __syncthreads();

  // GEMM2: out1T[dloc][p] = sum_c cmT[d][c]*xs[p][c]; cm panel q = 2d + (c>>7)
  f32x4 acc[2][2] = {};
  const u16* cbase = pbuf + (size_t)(dh*128)*2*prow + (size_t)tl*128;
  #pragma unroll
  for(int ks=0;ks<8;ks++){
    bf16x8 af[2], bf[2];
    #pragma unroll
    for(int mt=0;mt<2;mt++){
      const int dloc = w*32 + mt*16 + r15;
      af[mt] = *(const bf16x8*)(cbase + (size_t)dloc*2*prow + (size_t)(ks>>2)*prow + (ks&3)*32 + g*8);
    }
    #pragma unroll
    for(int nt=0;nt<2;nt++){
      const int p = nt*16 + r15;
      bf[nt] = *(const bf16x8*)&xs[p][ks*32 + g*8];
    }
    #pragma unroll
    for(int mt=0;mt<2;mt++)
      #pragma unroll
      for(int nt=0;nt<2;nt++)
        acc[mt][nt] = __builtin_amdgcn_mfma_f32_16x16x32_bf16(af[mt], bf[nt], acc[mt][nt], 0,0,0);
  }
  // epilogue -> o1[dloc][p] (gelu(x + m_beta[d]))
  #pragma unroll
  for(int mt=0;mt<2;mt++){
    const int d0 = w*32 + mt*16 + g*4;
    const f32x4 mb = *(const f32x4*)&m_beta[dh*128 + d0];
    #pragma unroll
    for(int nt=0;nt<2;nt++){
      const int p = nt*16 + r15;
      #pragma unroll
      for(int r=0;r<4;r++)
        o1[d0+r][p] = f2b(gelu_exact(acc[mt][nt][r] + mb[r]));
    }
  }
  __syncthreads();

  // GEMM-sm: out2T[dloc][o] = sum_p o1[dloc][p]*sm[o][p]  (K=32, single step)
  f32x4 acc2[2][2] = {};
  {
    bf16x8 af[2], bf2[2];
    #pragma unroll
    for(int mt=0;mt<2;mt++){
      const int dloc = w*32 + mt*16 + r15;
      af[mt] = *(const bf16x8*)&o1[dloc][g*8];
    }
    #pragma unroll
    for(int nt=0;nt<2;nt++){
      const int o = nt*16 + r15;
      bf2[nt] = *(const bf16x8*)&smt[o][g*8];
    }
    #pragma unroll
    for(int mt=0;mt<2;mt++)
      #pragma unroll
      for(int nt=0;nt<2;nt++)
        acc2[mt][nt] = __builtin_amdgcn_mfma_f32_16x16x32_bf16(af[mt], bf2[nt], acc2[mt][nt], 0,0,0);
  }
  // epilogue into xs buffer reused as out2 tile [o][dloc]
  u16 (*o2t)[264] = xs;
  #pragma unroll
  for(int nt=0;nt<2;nt++){
    const int o = nt*16 + r15;
    const float sb = s_beta[o];
    #pragma unroll
    for(int mt=0;mt<2;mt++){
      const int d0 = w*32 + mt*16 + g*4;
      u16x4 t4;
      #pragma unroll
      for(int r=0;r<4;r++) t4[r] = f2b(gelu_exact(acc2[mt][nt][r] + sb));
      *(u16x4*)&o2t[o][d0] = t4;
    }
  }
  __syncthreads();
  // copy out flat (k = o*256 + dh*128 + dd)
  {
    u16* dst = out2 + (size_t)tl*8192 + dh*128;
    #pragma unroll
    for(int i=0;i<2;i++){
      const int flat = (i*256 + tid)*8;   // over [o][128]
      const int o = flat >> 7, dd = flat & 127;
      *(u16x8*)(dst + o*256 + dd) = *(const u16x8*)&o2t[o][dd];
    }
  }
}

// ---------------- proj GEMM: 2-phase LDS-pipelined. part[kz][t][e] = sum_{k slice} out2[t][k]*pwb[e][k]
// grid (32, KSPL), 512 threads (8 waves: 2M x 4N; wave tile 32x64). BM=64, BN=256, Kslice=512, kstep=32.
__global__ __launch_bounds__(512) void k_proj(
    const u16* __restrict__ out2, const u16* __restrict__ pwb,
    float* __restrict__ part){
  __shared__ u16 Ab[2][64*32];
  __shared__ u16 Bb[2][256*32];
  const int tid = threadIdx.x;
  const int lane = tid & 63, w = tid >> 6;
  const int r15 = lane & 15, g = lane >> 4;
  const int m0 = blockIdx.x * 64;
  const int k0 = blockIdx.y * 512;
  const int wm = (w >> 2) * 32;
  const int wn = (w & 3) * 64;
  const int srow = lane >> 2;
  const int cs   = lane & 3;
  const int a_row = (w & 3)*16 + srow;
  const u16* a_src = out2 + (size_t)(m0 + a_row)*8192 + k0 + (size_t)((cs ^ (a_row & 3))*8);
  const int b_row0 = (2*w)*16 + srow;
  const int b_row1 = (2*w+1)*16 + srow;
  const u16* b_src0 = pwb + (size_t)b_row0*8192 + k0 + (size_t)((cs ^ (b_row0 & 3))*8);
  const u16* b_src1 = pwb + (size_t)b_row1*8192 + k0 + (size_t)((cs ^ (b_row1 & 3))*8);

  f32x4 acc[2][4] = {};

  #define STAGE(buf, kt) do{                                         \
    const int ko = (kt)*32;                                          \
    if(w < 4) gload16(a_src + ko, (char*)&Ab[buf][0] + w*1024);      \
    gload16(b_src0 + ko, (char*)&Bb[buf][0] + (2*w)*1024);           \
    gload16(b_src1 + ko, (char*)&Bb[buf][0] + (2*w+1)*1024);         \
  }while(0)

  STAGE(0, 0);
  __syncthreads();
  int cur = 0;
  for(int kt=0; kt<16; kt++){
    if(kt < 15){ STAGE(cur^1, kt+1); }
    bf16x8 af[2], bf[4];
    #pragma unroll
    for(int mt=0;mt<2;mt++){
      const int row = wm + mt*16 + r15;
      af[mt] = *(const bf16x8*)((char*)&Ab[cur][0] + row*64 + ((g ^ (row&3))*16));
    }
    #pragma unroll
    for(int nt=0;nt<4;nt++){
      const int row = wn + nt*16 + r15;
      bf[nt] = *(const bf16x8*)((char*)&Bb[cur][0] + row*64 + ((g ^ (row&3))*16));
    }
    #pragma unroll
    for(int mt=0;mt<2;mt++)
      #pragma unroll
      for(int nt=0;nt<4;nt++)
        acc[mt][nt] = __builtin_amdgcn_mfma_f32_16x16x32_bf16(af[mt], bf[nt], acc[mt][nt], 0,0,0);
    __syncthreads();
    cur ^= 1;
  }
  #undef STAGE

  float* pbase = part + (size_t)blockIdx.y*TKN*CDIM;
  #pragma unroll
  for(int mt=0;mt<2;mt++)
    #pragma unroll
    for(int nt=0;nt<4;nt++){
      const int t = m0 + wm + mt*16 + g*4;
      const int e = wn + nt*16 + r15;
      #pragma unroll
      for(int r=0;r<4;r++)
        pbase[(size_t)(t+r)*CDIM + e] = acc[mt][nt][r];
    }
}

// ---------------- combine partials + proj_b (f32x4 vectorized)
// 131072 threads total = 512 blocks x 256 (each thread owns one f32x4)
__global__ __launch_bounds__(256) void k_combine(
    const float* __restrict__ part, const float* __restrict__ pb,
    float* __restrict__ out){
  const int i4 = blockIdx.x*256 + threadIdx.x;   // 131072 f32x4's
  const int e4 = (i4 & 63)*4;
  f32x4 s = *(const f32x4*)&pb[e4];
  #pragma unroll
  for(int z=0;z<KSPL;z++) s += *(const f32x4*)&part[(size_t)z*524288 + (size_t)i4*4];
  *(f32x4*)&out[(size_t)i4*4] = s;
}

extern "C" void kernel_launch(void* const* d_in, const int* in_sizes, int n_in,
                              void* d_out, int out_size, void* d_ws, size_t ws_size,
                              hipStream_t stream){
  const float* x     = (const float*)d_in[0];
  const float* query = (const float*)d_in[1];
  const float* ln_w  = (const float*)d_in[2];
  const float* ln_b  = (const float*)d_in[3];
  const float* w1    = (const float*)d_in[4];
  const float* b1    = (const float*)d_in[5];
  const float* w2    = (const float*)d_in[6];
  const float* b2    = (const float*)d_in[7];
  const float* m_beta= (const float*)d_in[8];
  const float* s_beta= (const float*)d_in[9];
  const float* pw    = (const float*)d_in[10];
  const float* pb    = (const float*)d_in[11];
  float* out = (float*)d_out;
  char* ws = (char*)d_ws;

  // chunk size chosen from ws_size (deterministic: ws_size is fixed).
  // Big path needs ~192 MB (measured ws = 256 MiB).
  const size_t need_big = 192u*1024u*1024u;
  const int chnk = (ws_size >= need_big) ? 1024 : 256;
  const int nch  = TKN / chnk;

  size_t off = 0;
  u16* H     = (u16*)(ws + off);  off += (size_t)TKN*HIDD*2;
  u16* w2s   = (u16*)(ws + off);  off += (size_t)TOTSZ*HIDD*2;
  float* b2p = (float*)(ws + off);off += (size_t)TOTSZ*4;
  u16* pwb   = (u16*)(ws + off);  off += (size_t)CDIM*8192*2;
  u16* pbuf  = (u16*)(ws + off);  off += (size_t)chnk*TOTSZ*2;   // 520 panels x chnk x 128
  u16* out2  = (u16*)(ws + off);  off += (size_t)TKN*8192*2;
  // part (16 x 2048 x 256 fp32 = 33.55 MB) aliases pbuf (>=34 MB, dead by k_proj).
  float* part= (float*)pbuf;

  k_prep_h<<<TKN, 256, 0, stream>>>(query, ln_w, ln_b, w1, b1, H);
  k_prep_w2<<<4160, 256, 0, stream>>>(w2, b2, w2s, b2p);
  k_prep_pw<<<1024, 256, 0, stream>>>(pw, pwb);
  for(int ch=0; ch<nch; ch++){
    k_params<<<dim3(520,2), 256, 0, stream>>>(H + (size_t)ch*chnk*HIDD, w2s, b2p, pbuf,
                                              chnk/128, chnk);
    k_token<<<dim3(chnk,2), 256, 0, stream>>>(x + (size_t)ch*chnk*8192, pbuf, m_beta, s_beta,
                                              out2 + (size_t)ch*chnk*8192, chnk);
  }
  k_proj<<<dim3(32,KSPL), 512, 0, stream>>>(out2, pwb, part);
  k_combine<<<512, 256, 0, stream>>>(part, pb, out);
}